// Round 6
// baseline (397.258 us; speedup 1.0000x reference)
//
#include <hip/hip_runtime.h>

// Problem constants
#define NB    2048   // n_back (k), innermost dim
#define NB4   512    // NB/4 in float4 units
#define NOUT  2048   // H*W*COUT
#define NDIM  2048   // H*W*CIN

// Output flat offsets (floats) in d_out: [w_u_, b_u_, w_l_, b_l_]
#define OFF_BU  16777216ull
#define OFF_WL  16785408ull
#define OFF_BL  33562624ull

typedef float f32x4 __attribute__((ext_vector_type(4)));

// k-partitioned XCD mapping (round-robin linear-block -> XCD assumed):
//   x & 7  = kc  (k-eighth, 64 f32x4 = 1KB per i-row)  -> XCD id
//   x >> 3 = pos (0..31): hi = pos&15 (fastest: hi+-1 L2 reuse distance = 1),
//            wh = pos>>4 (wi half)
//   z      = slice (t,b); dispatched last -> each XCD streams slice by slice.
// The 3x3 stencil never mixes k => ZERO cross-XCD halo duplication.
// Per-XCD per-slice input footprint = 2048 rows x 1KB = 2MB < 4MB L2.
// Threads: 256 = 64 k-lanes x 4 wi-pair sub-waves (wave-uniform wp).
__global__ __launch_bounds__(256, 4) void conv_back_kernel(
    const float* __restrict__ wu,
    const float* __restrict__ wl,
    const float* __restrict__ kern,   // (3,3,8,8) [kh][kw][ci][co]
    const float* __restrict__ bias,   // (8)
    float* __restrict__ out,          // full d_out base
    float* __restrict__ bias_ws)      // (2,4,2048) partial bias sums
{
    const int x   = blockIdx.x;              // 0..255
    const int z   = blockIdx.z;              // 0..7
    const int tid = threadIdx.x;             // 0..255
    const int kc  = x & 7;                   // k-eighth -> XCD
    const int pos = x >> 3;                  // 0..31
    const int hi  = pos & 15;
    const int wh  = pos >> 4;                // 0..1 wi half
    const int t   = z >> 2;
    const int b   = z & 3;
    const int kl  = tid & 63;                // k lane within eighth
    const int sub = tid >> 6;                // 0..3 wi-pair sub-wave
    const int wp  = (wh * 4 + sub) * 2;      // wi pair base: 0,2,...,14
    const int k4  = kc * 64 + kl;            // float4 index over k, 0..511

    const f32x4* win4 = (const f32x4*)(t ? wl : wu) + (size_t)b * NOUT * NB4 + k4;
    f32x4* wout4 = (f32x4*)(out + (t ? OFF_WL : 0)) + (size_t)b * NDIM * NB4 + k4;

    f32x4 acc[8][2];
    #pragma unroll
    for (int ci = 0; ci < 8; ++ci) {
        acc[ci][0] = (f32x4)(0.f);
        acc[ci][1] = (f32x4)(0.f);
    }
    f32x4 pb = (f32x4)(0.f);

    // wave-uniform edge masks: only wo = wp-1 and wp+2 can be out of range
    const bool vlo = (wp - 1) >= 0;
    const bool vhi = (wp + 2) < 16;

    #pragma unroll
    for (int dh = -1; dh <= 1; ++dh) {
        const int ho = hi + dh;
        if ((unsigned)ho < 16u) {            // block-uniform branch
            const f32x4* rowb = win4 + (size_t)(ho * 16 * 8) * NB4;
            #pragma unroll
            for (int co = 0; co < 8; ++co) {
                // the 4 distinct wi positions wp-1 .. wp+2, loaded once
                f32x4 u[4];
                u[0] = vlo ? rowb[(size_t)((wp - 1) * 8 + co) * NB4] : (f32x4)(0.f);
                u[1] = rowb[(size_t)((wp    ) * 8 + co) * NB4];
                u[2] = rowb[(size_t)((wp + 1) * 8 + co) * NB4];
                u[3] = vhi ? rowb[(size_t)((wp + 2) * 8 + co) * NB4] : (f32x4)(0.f);

                if (dh == 0) {
                    // o = (hi, wp, co) and (hi, wp+1, co): owned once across grid
                    pb += bias[co] * (u[1] + u[2]);
                }
                #pragma unroll
                for (int dw = -1; dw <= 1; ++dw) {
                    const int kb = ((1 - dh) * 3 + (1 - dw)) * 64 + co;
                    #pragma unroll
                    for (int ci = 0; ci < 8; ++ci) {
                        const float Kv = kern[kb + ci * 8];   // uniform -> SGPR
                        acc[ci][0] += Kv * u[dw + 1];
                        acc[ci][1] += Kv * u[dw + 2];
                    }
                }
            }
        }
    }

    #pragma unroll
    for (int ci = 0; ci < 8; ++ci)
        #pragma unroll
        for (int w4 = 0; w4 < 2; ++w4) {
            const int i = (hi * 16 + wp + w4) * 8 + ci;
            wout4[(size_t)i * NB4] = acc[ci][w4];   // plain full-line stores
        }

    // reduce bias partials across the 4 sub-waves (same k4 set), then one
    // wave of atomics; each XCD's atomic k-range is disjoint -> L2-local.
    __shared__ f32x4 red[3][64];
    if (sub > 0) red[sub - 1][kl] = pb;
    __syncthreads();
    if (sub == 0) {
        pb += red[0][kl] + red[1][kl] + red[2][kl];
        float* bws = bias_ws + t * 8192 + b * 2048 + 4 * k4;
        atomicAdd(bws + 0, pb.x);
        atomicAdd(bws + 1, pb.y);
        atomicAdd(bws + 2, pb.z);
        atomicAdd(bws + 3, pb.w);
    }
}

// b_out_ = b_in + ws ; 16384 outputs (2 ul * 4 b * 2048 k)
__global__ void bias_finalize(const float* __restrict__ bu,
                              const float* __restrict__ bl,
                              const float* __restrict__ ws,
                              float* __restrict__ out)
{
    const int idx = blockIdx.x * blockDim.x + threadIdx.x;   // 0..16383
    const int ul  = idx >> 13;
    const int r   = idx & 8191;                              // b*2048 + k
    const float* bin = ul ? bl : bu;
    const size_t off = ul ? OFF_BL : OFF_BU;
    out[off + r] = bin[r] + ws[(size_t)ul * 8192 + r];
}

extern "C" void kernel_launch(void* const* d_in, const int* in_sizes, int n_in,
                              void* d_out, int out_size, void* d_ws, size_t ws_size,
                              hipStream_t stream) {
    // inputs: 0=x (unused), 1=kernel, 2=bias, 3=w_out_u, 4=b_out_u, 5=w_out_l, 6=b_out_l
    const float* kern = (const float*)d_in[1];
    const float* bias = (const float*)d_in[2];
    const float* wu   = (const float*)d_in[3];
    const float* bu   = (const float*)d_in[4];
    const float* wl   = (const float*)d_in[5];
    const float* bl   = (const float*)d_in[6];
    float* out = (float*)d_out;
    float* ws  = (float*)d_ws;

    // zero the 64 KB bias-partial region (graph replays re-run this node)
    (void)hipMemsetAsync(ws, 0, 2ull * 4 * NB * sizeof(float), stream);

    conv_back_kernel<<<dim3(256, 1, 8), dim3(256), 0, stream>>>(wu, wl, kern, bias, out, ws);
    bias_finalize<<<64, 256, 0, stream>>>(bu, bl, ws, out);
}

// Round 7
// 265.283 us; speedup vs baseline: 1.4975x; 1.4975x over previous
//
#include <hip/hip_runtime.h>

// Problem constants
#define NB    2048   // n_back (k), innermost dim of w tensors
#define NOUT  2048   // H*W*COUT
#define NDIM  2048   // H*W*CIN

// Output flat offsets (floats) in d_out: [w_u_, b_u_, w_l_, b_l_]
#define OFF_BU  16777216ull
#define OFF_WL  16785408ull
#define OFF_BL  33562624ull

// Rolling-window conv-backward. One wave owns (wp: wi-pair, hs: 8-row hi
// half, kc: 64-float k chunk, t,b). It marches ho = r0-1 .. r0+8 keeping
// THREE output-row accumulators in registers:
//   in-row ho contributes to out rows ho-1 (kh=0), ho (kh=1), ho+1 (kh=2).
// Each input element is loaded ONCE per wave (stencil reuse in registers,
// not cache). Block = 4 waves = adjacent wp (0..3 or 4..7) sharing the same
// k-chunk, so wi-seam loads overlap in L1 (20KB/row working set).
// Read amp model: 1.25 (hi halo) x 1.25 (wi seams via L1) ~ 210 MB HBM.
__global__ __launch_bounds__(256, 4) void conv_back_kernel(
    const float* __restrict__ wu,
    const float* __restrict__ wl,
    const float* __restrict__ kern,   // (3,3,8,8) [kh][kw][ci][co]
    const float* __restrict__ bias,   // (8)
    float* __restrict__ outbuf,       // full d_out base
    float* __restrict__ bias_ws)      // (2,4,2048) partial bias sums
{
    const int bx  = blockIdx.x;            // 0..63 : wpg*32 + kc  (XCD = kc&7)
    const int hs  = blockIdx.y;            // 0..1  : hi half
    const int z   = blockIdx.z;            // 0..7  : (t,b)
    const int kc  = bx & 31;
    const int wpg = bx >> 5;
    const int t   = z >> 2;
    const int b   = z & 3;
    const int kl  = threadIdx.x & 63;      // k lane
    const int sub = threadIdx.x >> 6;      // 0..3 sub-wave
    const int wp  = wpg * 4 + sub;         // wi pair id 0..7
    const int wb  = wp * 2;                // wi base 0..14
    const int r0  = hs * 8;                // first owned out row
    const int k   = kc * 64 + kl;

    const float* __restrict__ in = (t ? wl : wu) + (size_t)b * NOUT * NB + k;
    float* __restrict__ wout = outbuf + (t ? OFF_WL : 0) + (size_t)b * NDIM * NB + k;

    const bool vlo = wp > 0;               // wave-uniform wi edge masks
    const bool vhi = wp < 7;

    // acc invariants at start of step s (ho = r0-1+s):
    //   a0 = out row ho-1, a1 = out row ho, a2 = out row ho+1 (partial sums)
    float a0[16], a1[16], a2[16];          // [j*8+ci], j = owned wi offset
    #pragma unroll
    for (int i = 0; i < 16; ++i) { a0[i] = 0.f; a1[i] = 0.f; a2[i] = 0.f; }
    float pb = 0.f;

    for (int s = 0; s < 10; ++s) {
        const int ho = r0 - 1 + s;
        float u[4][8];                     // wi = wb-1 .. wb+2, co = 0..7
        if ((unsigned)ho < 16u) {          // block-uniform
            const float* rowb = in + (size_t)(ho * 16 * 8) * NB;
            #pragma unroll
            for (int co = 0; co < 8; ++co) {
                u[0][co] = vlo ? rowb[(size_t)((wb - 1) * 8 + co) * NB] : 0.f;
                u[1][co] = rowb[(size_t)((wb    ) * 8 + co) * NB];
                u[2][co] = rowb[(size_t)((wb + 1) * 8 + co) * NB];
                u[3][co] = vhi ? rowb[(size_t)((wb + 2) * 8 + co) * NB] : 0.f;
            }
        } else {
            #pragma unroll
            for (int w4 = 0; w4 < 4; ++w4)
                #pragma unroll
                for (int co = 0; co < 8; ++co) u[w4][co] = 0.f;
        }

        if (s >= 1 && s <= 8) {            // ho is an owned row: bias terms
            #pragma unroll
            for (int co = 0; co < 8; ++co)
                pb += bias[co] * (u[1][co] + u[2][co]);
        }

        // in-row ho -> out rows ho-1 (kh=0), ho (kh=1), ho+1 (kh=2)
        #pragma unroll
        for (int j = 0; j < 2; ++j)
            #pragma unroll
            for (int dw = -1; dw <= 1; ++dw) {
                const int kwq = (1 - dw) * 64;     // kw block offset
                #pragma unroll
                for (int co = 0; co < 8; ++co) {
                    const float uv = u[j + 1 + dw][co];
                    #pragma unroll
                    for (int ci = 0; ci < 8; ++ci) {
                        a0[j*8+ci] += kern[        kwq + ci*8 + co] * uv;  // kh=0
                        a1[j*8+ci] += kern[3*64  + kwq + ci*8 + co] * uv;  // kh=1
                        a2[j*8+ci] += kern[6*64  + kwq + ci*8 + co] * uv;  // kh=2
                    }
                }
            }

        if (s >= 2) {                      // out row r = ho-1 is complete
            const int r = ho - 1;          // r0 .. r0+7
            #pragma unroll
            for (int j = 0; j < 2; ++j)
                #pragma unroll
                for (int ci = 0; ci < 8; ++ci)
                    wout[(size_t)((r * 16 + wb + j) * 8 + ci) * NB] = a0[j*8+ci];
        }

        // rotate accumulators (static indices only -> stays in registers)
        #pragma unroll
        for (int i = 0; i < 16; ++i) { a0[i] = a1[i]; a1[i] = a2[i]; a2[i] = 0.f; }
    }

    // reduce bias partials across the 4 sub-waves, one atomic wave per block
    __shared__ float red[4][64];
    red[sub][kl] = pb;
    __syncthreads();
    if (sub == 0) {
        const float tot = red[0][kl] + red[1][kl] + red[2][kl] + red[3][kl];
        atomicAdd(&bias_ws[t * 8192 + b * 2048 + k], tot);
    }
}

// b_out_ = b_in + ws ; 16384 outputs (2 ul * 4 b * 2048 k)
__global__ void bias_finalize(const float* __restrict__ bu,
                              const float* __restrict__ bl,
                              const float* __restrict__ ws,
                              float* __restrict__ out)
{
    const int idx = blockIdx.x * blockDim.x + threadIdx.x;   // 0..16383
    const int ul  = idx >> 13;
    const int r   = idx & 8191;                              // b*2048 + k
    const float* bin = ul ? bl : bu;
    const size_t off = ul ? OFF_BL : OFF_BU;
    out[off + r] = bin[r] + ws[(size_t)ul * 8192 + r];
}

extern "C" void kernel_launch(void* const* d_in, const int* in_sizes, int n_in,
                              void* d_out, int out_size, void* d_ws, size_t ws_size,
                              hipStream_t stream) {
    // inputs: 0=x (unused), 1=kernel, 2=bias, 3=w_out_u, 4=b_out_u, 5=w_out_l, 6=b_out_l
    const float* kern = (const float*)d_in[1];
    const float* bias = (const float*)d_in[2];
    const float* wu   = (const float*)d_in[3];
    const float* bu   = (const float*)d_in[4];
    const float* wl   = (const float*)d_in[5];
    const float* bl   = (const float*)d_in[6];
    float* out = (float*)d_out;
    float* ws  = (float*)d_ws;

    // zero the 64 KB bias-partial region (graph replays re-run this node)
    (void)hipMemsetAsync(ws, 0, 2ull * 4 * NB * sizeof(float), stream);

    conv_back_kernel<<<dim3(64, 2, 8), dim3(256), 0, stream>>>(wu, wl, kern, bias, out, ws);
    bias_finalize<<<64, 256, 0, stream>>>(bu, bl, ws, out);
}